// Round 1
// baseline (180690.552 us; speedup 1.0000x reference)
//
#include <hip/hip_runtime.h>

#define T_TOTAL 131072

__device__ __forceinline__ float sigf(float x) {
  return 1.f / (1.f + __expf(-x));
}
__device__ __forceinline__ float tanhfast(float x) {
  // 1 - 2/(e^{2x}+1); saturates correctly for |x| large (inf -> 1, 0 -> -1)
  return 1.f - 2.f / (__expf(2.f * x) + 1.f);
}

// ---------- input-projection GEMM: out[r][j] = ba[j]+bb[j] + sum_k W[j][k]*in[r][k]
// in: [rows, K], W: [512, K], out: [rows, 512]; grid = rows/64, block = 512
template<int K>
__global__ __launch_bounds__(512) void pre_gemm(
    const float* __restrict__ in, const float* __restrict__ W,
    const float* __restrict__ ba, const float* __restrict__ bb,
    float* __restrict__ out)
{
  __shared__ float tile[64 * K];
  const int tid = threadIdx.x;
  const size_t t0 = (size_t)blockIdx.x * 64;
  for (int i = tid; i < 64 * K; i += 512) tile[i] = in[t0 * K + i];
  __syncthreads();
  const int j = tid;  // 512 output columns
  const float bias = ba[j] + bb[j];
  float acc[64];
#pragma unroll
  for (int r = 0; r < 64; ++r) acc[r] = 0.f;
  for (int kb = 0; kb < K; kb += 8) {
    float wv[8];
#pragma unroll
    for (int k = 0; k < 8; ++k) wv[k] = W[j * K + kb + k];
#pragma unroll
    for (int r = 0; r < 64; ++r) {
#pragma unroll
      for (int k = 0; k < 8; ++k) acc[r] = fmaf(wv[k], tile[r * K + kb + k], acc[r]);
    }
  }
#pragma unroll
  for (int r = 0; r < 64; ++r) out[(t0 + r) * 512 + j] = acc[r] + bias;
}

// ---------- sequential LSTM recurrence over one chunk.
// pre: [nsteps,512] (x-projection + both biases already applied)
// hout: [nsteps,128]; Whh: [512,128]; carry: [h(128), c(128)]
// 1 block x 512 threads. thread = (kchunk = tid>>7 in 0..3, jj = tid&127)
// thread accumulates rows {jj, 128+jj, 256+jj, 384+jj} over k in [kc*32, kc*32+32)
__global__ __launch_bounds__(512) void lstm_rec(
    const float* __restrict__ pre,
    float* __restrict__ hout,
    const float* __restrict__ Whh,
    float* __restrict__ carry,
    int nsteps)
{
  __shared__ float hbuf[128];
  __shared__ float4 pbuf[4][128];
  const int tid = threadIdx.x;
  const int kc = tid >> 7, jj = tid & 127;

  float w[4][32];
#pragma unroll
  for (int g = 0; g < 4; ++g) {
    const float* wr = Whh + (g * 128 + jj) * 128 + kc * 32;
#pragma unroll
    for (int k = 0; k < 32; k += 4) {
      const float4 v = *reinterpret_cast<const float4*>(wr + k);
      w[g][k] = v.x; w[g][k + 1] = v.y; w[g][k + 2] = v.z; w[g][k + 3] = v.w;
    }
  }

  float c_state = 0.f;
  if (tid < 128) {
    hbuf[jj] = carry[jj];
    c_state = carry[128 + jj];
  }
  __syncthreads();

  for (int t = 0; t < nsteps; ++t) {
    // prefetch pre-row for this step (consumed after the barrier)
    float4 pr = {0.f, 0.f, 0.f, 0.f};
    if (tid < 128) {
      const float* p = pre + (size_t)t * 512 + jj;
      pr.x = p[0]; pr.y = p[128]; pr.z = p[256]; pr.w = p[384];
    }
    // phase A: partial dots, h broadcast from LDS (wave-uniform addresses)
    float2 a0 = {0.f, 0.f}, a1 = {0.f, 0.f}, a2 = {0.f, 0.f}, a3 = {0.f, 0.f};
    const float* hb = hbuf + kc * 32;
#pragma unroll
    for (int k = 0; k < 32; k += 2) {
      const float2 h2 = *reinterpret_cast<const float2*>(hb + k);
      a0.x = fmaf(w[0][k], h2.x, a0.x); a0.y = fmaf(w[0][k + 1], h2.y, a0.y);
      a1.x = fmaf(w[1][k], h2.x, a1.x); a1.y = fmaf(w[1][k + 1], h2.y, a1.y);
      a2.x = fmaf(w[2][k], h2.x, a2.x); a2.y = fmaf(w[2][k + 1], h2.y, a2.y);
      a3.x = fmaf(w[3][k], h2.x, a3.x); a3.y = fmaf(w[3][k + 1], h2.y, a3.y);
    }
    float4 ps;
    ps.x = a0.x + a0.y; ps.y = a1.x + a1.y;
    ps.z = a2.x + a2.y; ps.w = a3.x + a3.y;
    pbuf[kc][jj] = ps;
    __syncthreads();
    // phase B: reduce 4 k-chunks, gates, state update (waves 0-1 only)
    if (tid < 128) {
      const float4 s0 = pbuf[0][jj], s1 = pbuf[1][jj], s2 = pbuf[2][jj], s3 = pbuf[3][jj];
      const float zi = s0.x + s1.x + s2.x + s3.x + pr.x;
      const float zf = s0.y + s1.y + s2.y + s3.y + pr.y;
      const float zg = s0.z + s1.z + s2.z + s3.z + pr.z;
      const float zo = s0.w + s1.w + s2.w + s3.w + pr.w;
      const float ig = sigf(zi);
      const float fg = sigf(zf);
      const float gg = tanhfast(zg);
      const float og = sigf(zo);
      c_state = fmaf(fg, c_state, ig * gg);
      const float h = og * tanhfast(c_state);
      hbuf[jj] = h;
      hout[(size_t)t * 128 + jj] = h;
    }
    __syncthreads();
  }
  if (tid < 128) {
    carry[jj] = hbuf[jj];
    carry[128 + jj] = c_state;
  }
}

// ---------- MLP block: out = LeakyReLU( (AFFINE ? a*in+c : in) @ W^T + b )
// emits per-block BN partial sums (sum, sumsq) of the post-activation output.
// in: [T,KI], W: [KO,KI], out: [T,KO], part: [nblk, 2*KO]; 64 rows/block, 256 thr
template<int KI, int KO, bool AFFINE>
__global__ __launch_bounds__(256) void mlp_block(
    const float* __restrict__ in, const float* __restrict__ W,
    const float* __restrict__ bias, const float* __restrict__ ac,
    float* __restrict__ out, float* __restrict__ part)
{
  constexpr int NR = 256 / KO;
  __shared__ float Wl[KO * KI];
  __shared__ float badj[KO];
  __shared__ float red[2][256];
  const int tid = threadIdx.x;
  const int j = tid % KO, rsub = tid / KO;

  for (int i = tid; i < KO * KI; i += 256) {
    float wv = W[i];
    if constexpr (AFFINE) wv *= ac[i % KI];
    Wl[i] = wv;
  }
  if (tid < KO) {
    float s = bias[tid];
    if constexpr (AFFINE) {
      for (int k = 0; k < KI; ++k) s = fmaf(W[tid * KI + k], ac[KI + k], s);
    }
    badj[tid] = s;
  }
  __syncthreads();

  const size_t t0 = (size_t)blockIdx.x * 64;
  float psum = 0.f, psq = 0.f;
  for (int r = rsub; r < 64; r += NR) {
    const float* row = in + (t0 + r) * KI;
    float acc = badj[j];
#pragma unroll
    for (int k = 0; k < KI; ++k) acc = fmaf(Wl[j * KI + k], row[k], acc);
    const float y = acc >= 0.f ? acc : 0.01f * acc;
    out[(t0 + r) * KO + j] = y;
    psum += y; psq += y * y;
  }
  red[0][tid] = psum; red[1][tid] = psq;
  __syncthreads();
  if (tid < KO) {
    float s = 0.f, q = 0.f;
#pragma unroll
    for (int rr = 0; rr < NR; ++rr) { s += red[0][rr * KO + tid]; q += red[1][rr * KO + tid]; }
    part[(size_t)blockIdx.x * (2 * KO) + tid] = s;
    part[(size_t)blockIdx.x * (2 * KO) + KO + tid] = q;
  }
}

// ---------- fold BN stats into per-feature affine: a = g/sd, c = be - m*a
__global__ __launch_bounds__(64) void bn_reduce(
    const float* __restrict__ part, const float* __restrict__ gamma,
    const float* __restrict__ beta, float* __restrict__ ac,
    int nblk, int KO, float invT)
{
  const int j = threadIdx.x;
  if (j >= KO) return;
  float s = 0.f, q = 0.f;
  for (int b = 0; b < nblk; ++b) {
    s += part[(size_t)b * 2 * KO + j];
    q += part[(size_t)b * 2 * KO + KO + j];
  }
  const float m = s * invT;
  const float v = q * invT - m * m;           // biased variance (matches jnp.var)
  const float inv = 1.f / sqrtf(v + 1e-5f);
  const float a = gamma[j] * inv;
  ac[j] = a;
  ac[KO + j] = beta[j] - m * a;
}

// ---------- final projection: out[t] = bo + sum_k wo[k]*(a[k]*y3[t,k]+c[k])
__global__ __launch_bounds__(256) void final_out(
    const float* __restrict__ y3, const float* __restrict__ wo,
    const float* __restrict__ bo, const float* __restrict__ ac,
    float* __restrict__ out)
{
  const size_t t = (size_t)blockIdx.x * 256 + threadIdx.x;
  float acc = bo[0];
#pragma unroll
  for (int k = 0; k < 16; ++k) acc = fmaf(wo[k], ac[16 + k], acc);  // + wo.c
#pragma unroll
  for (int k = 0; k < 16; ++k) acc = fmaf(wo[k] * ac[k], y3[t * 16 + k], acc);
  out[t] = acc;
}

extern "C" void kernel_launch(void* const* d_in, const int* in_sizes, int n_in,
                              void* d_out, int out_size, void* d_ws, size_t ws_size,
                              hipStream_t stream) {
  const float* x    = (const float*)d_in[0];
  const float* Wih0 = (const float*)d_in[1];
  const float* Whh0 = (const float*)d_in[2];
  const float* bih0 = (const float*)d_in[3];
  const float* bhh0 = (const float*)d_in[4];
  const float* Wih1 = (const float*)d_in[5];
  const float* Whh1 = (const float*)d_in[6];
  const float* bih1 = (const float*)d_in[7];
  const float* bhh1 = (const float*)d_in[8];
  const float* w1 = (const float*)d_in[9];  const float* b1 = (const float*)d_in[10];
  const float* g1 = (const float*)d_in[11]; const float* be1 = (const float*)d_in[12];
  const float* w2 = (const float*)d_in[13]; const float* b2 = (const float*)d_in[14];
  const float* g2 = (const float*)d_in[15]; const float* be2 = (const float*)d_in[16];
  const float* w3 = (const float*)d_in[17]; const float* b3 = (const float*)d_in[18];
  const float* g3 = (const float*)d_in[19]; const float* be3 = (const float*)d_in[20];
  const float* wo = (const float*)d_in[21]; const float* bo = (const float*)d_in[22];
  float* out = (float*)d_out;

  const int T = T_TOTAL;
  const size_t MB = 1ull << 20;

  // pick chunk length so the workspace fits (fixed part = 4MB stats + 120MB tensors)
  int CH = 16384;
  const size_t fixed = 4 * MB + (64 + 32 + 16 + 8) * MB;
  while (CH > 1024 && fixed + (size_t)CH * 4608 > ws_size) CH >>= 1;
  const int NC = T / CH;

  char* w8 = (char*)d_ws;
  float* carry0 = (float*)(w8);                    // 256 f
  float* carry1 = (float*)(w8 + 1024);             // 256 f
  float* ac1    = (float*)(w8 + 4096);             // 128 f
  float* ac2    = (float*)(w8 + 4096 + 1024);      // 64 f
  float* ac3    = (float*)(w8 + 4096 + 2048);      // 32 f
  float* part1  = (float*)(w8 + 64 * 1024);        // 2048*128 f = 1MB
  float* part2  = (float*)(w8 + 64 * 1024 + MB);   // 2048*64 f
  float* part3  = (float*)(w8 + 64 * 1024 + MB + MB / 2);
  char* big = w8 + 4 * MB;
  float* h1   = (float*)(big);                     // [T,128] 64MB
  float* y1   = (float*)(big + 64 * MB);           // [T,64]  32MB
  float* y2   = (float*)(big + 96 * MB);           // [T,32]  16MB
  float* y3   = (float*)(big + 112 * MB);          // [T,16]   8MB
  float* pre0 = (float*)(big + 120 * MB);          // [CH,512]
  float* pre1 = pre0 + (size_t)CH * 512;           // [CH,512]
  float* h0b  = pre1 + (size_t)CH * 512;           // [CH,128]

  hipMemsetAsync(d_ws, 0, 2048, stream);  // zero both carries every call

  for (int c = 0; c < NC; ++c) {
    pre_gemm<8><<<CH / 64, 512, 0, stream>>>(x + (size_t)c * CH * 8, Wih0, bih0, bhh0, pre0);
    lstm_rec<<<1, 512, 0, stream>>>(pre0, h0b, Whh0, carry0, CH);
    pre_gemm<128><<<CH / 64, 512, 0, stream>>>(h0b, Wih1, bih1, bhh1, pre1);
    lstm_rec<<<1, 512, 0, stream>>>(pre1, h1 + (size_t)c * CH * 128, Whh1, carry1, CH);
  }

  mlp_block<128, 64, false><<<T / 64, 256, 0, stream>>>(h1, w1, b1, nullptr, y1, part1);
  bn_reduce<<<1, 64, 0, stream>>>(part1, g1, be1, ac1, T / 64, 64, 1.f / T);
  mlp_block<64, 32, true><<<T / 64, 256, 0, stream>>>(y1, w2, b2, ac1, y2, part2);
  bn_reduce<<<1, 64, 0, stream>>>(part2, g2, be2, ac2, T / 64, 32, 1.f / T);
  mlp_block<32, 16, true><<<T / 64, 256, 0, stream>>>(y2, w3, b3, ac2, y3, part3);
  bn_reduce<<<1, 64, 0, stream>>>(part3, g3, be3, ac3, T / 64, 16, 1.f / T);
  final_out<<<T / 256, 256, 0, stream>>>(y3, wo, bo, ac3, out);
}